// Round 1
// baseline (701.219 us; speedup 1.0000x reference)
//
#include <hip/hip_runtime.h>
#include <math.h>

// Problem constants (fixed by setup_inputs)
#define BB   128
#define TTW  16      // t (window length)
#define FEATN 256
#define NNODE 1024
#define NEDGE 8192

// d_out layout (float elements)
#define OUT_MX    0
#define OUT_NODES (BB*TTW*FEATN)                     // 524288
#define OUT_EDGES (OUT_NODES + BB*NNODE*FEATN)       // 34078720
#define OUT_W     (OUT_EDGES + BB*2*NEDGE)           // 36175872
#define OUT_TT    (OUT_W + BB*NEDGE)                 // 37224448

// ---------------- passthrough / scatter ----------------

__global__ void k_copy_nodes(const float4* __restrict__ src, float4* __restrict__ dst, int n4) {
    int i = blockIdx.x * blockDim.x + threadIdx.x;
    int stride = gridDim.x * blockDim.x;
    for (; i < n4; i += stride) dst[i] = src[i];
}

// scatter x rows into node buffer: out_nodes[b, T[b]+i, :] = x[b, i, :]
__global__ void k_scatter_x(const float4* __restrict__ x4, const int* __restrict__ T,
                            float4* __restrict__ nodes4) {
    int idx = blockIdx.x * 256 + threadIdx.x;   // 131072 float4s total
    int b  = idx >> 10;            // 16 rows * 64 f4/row = 1024 per batch
    int ri = (idx >> 6) & 15;
    int f  = idx & 63;
    int row = T[b] + ri;
    nodes4[(size_t)b * (NNODE * 64) + row * 64 + f] = x4[idx];
}

__global__ void k_misc(const int* __restrict__ edges, const float* __restrict__ w,
                       const int* __restrict__ T, const int* __restrict__ taus,
                       float* __restrict__ out) {
    int i = blockIdx.x * blockDim.x + threadIdx.x;
    const int ne = BB * 2 * NEDGE;   // 2097152
    const int nw = BB * NEDGE;       // 1048576
    if (i < ne) out[OUT_EDGES + i] = (float)edges[i];
    if (i < nw) out[OUT_W + i] = w[i];
    if (i < BB) out[OUT_TT + i] = (float)(T[i] + taus[i]);
}

// ---------------- bucket edges by dst (counting sort per batch) ----------------

__global__ void k_bucket(const int* __restrict__ edges, const float* __restrict__ w,
                         int2* __restrict__ sw, int* __restrict__ bstart) {
    int b = blockIdx.x;
    int tid = threadIdx.x;
    __shared__ int cnt[256];
    __shared__ int pos[256];
    cnt[tid] = 0;
    __syncthreads();
    const int* src = edges + (size_t)b * 2 * NEDGE;
    const int* dst = src + NEDGE;
    for (int e = tid; e < NEDGE; e += 256) {
        int d = dst[e];
        atomicAdd(&cnt[d], 1);
    }
    __syncthreads();
    int my = cnt[tid];
    int v = my;
    // Hillis-Steele inclusive scan over 256 counts
    for (int off = 1; off < 256; off <<= 1) {
        int u = 0;
        if (tid >= off) u = cnt[tid - off];
        __syncthreads();
        cnt[tid] = v = v + u;
        __syncthreads();
    }
    int start = v - my;   // exclusive prefix
    bstart[b * 264 + tid] = start;
    if (tid == 0) bstart[b * 264 + 256] = NEDGE;
    pos[tid] = start;
    __syncthreads();
    const float* wb = w + (size_t)b * NEDGE;
    for (int e = tid; e < NEDGE; e += 256) {
        int d = dst[e];
        int p = atomicAdd(&pos[d], 1);
        sw[(size_t)b * NEDGE + p] = make_int2(src[e], __float_as_int(wb[e]));
    }
}

// ---------------- agg1: one wave per (batch, dst-row in 0..255) ----------------

__global__ void k_agg1(const float* __restrict__ nodes, const int2* __restrict__ sw,
                       const int* __restrict__ bstart, float* __restrict__ agg1) {
    int b = blockIdx.x >> 6;
    int d = ((blockIdx.x & 63) << 2) + (threadIdx.x >> 6);
    int lane = threadIdx.x & 63;
    int e0 = bstart[b * 264 + d];
    int e1 = bstart[b * 264 + d + 1];
    const float4* nb = (const float4*)(nodes + (size_t)b * NNODE * FEATN);
    const int2* swb = sw + (size_t)b * NEDGE;
    float4 acc = make_float4(0.f, 0.f, 0.f, 0.f);
    for (int e = e0; e < e1; ++e) {
        int2 p = swb[e];
        float wt = __int_as_float(p.y);
        float4 vv = nb[p.x * 64 + lane];
        acc.x = fmaf(wt, vv.x, acc.x);
        acc.y = fmaf(wt, vv.y, acc.y);
        acc.z = fmaf(wt, vv.z, acc.z);
        acc.w = fmaf(wt, vv.w, acc.w);
    }
    ((float4*)(agg1 + ((size_t)b * 256 + d) * FEATN))[lane] = acc;
}

// ---------------- gemm1: h1[b, r] = tanh(node_row @ Ws1 + agg_row @ Wm1) ----------------
// rows r: 0..255 -> node r / agg r ;  256..271 -> node T+i / agg (T+i<256 ? T+i : 0)
// M-tile 64, microtile 16 rows x 4 cols per thread, KT=32, K=512 (concat)

__launch_bounds__(256, 2)
__global__ void k_gemm1(const float* __restrict__ nodes, const float* __restrict__ agg1,
                        const float* __restrict__ Ws, const float* __restrict__ Wm,
                        const int* __restrict__ T, float* __restrict__ h1) {
    int b = blockIdx.x / 5;
    int tile = blockIdx.x % 5;
    int tid = threadIdx.x;
    int c = tid & 63;
    int rg = tid >> 6;   // 0..3 -> rows rg*16..+15 of the tile
    __shared__ float XS[64][36];
    float acc[16][4];
#pragma unroll
    for (int r = 0; r < 16; ++r)
#pragma unroll
        for (int m = 0; m < 4; ++m) acc[r][m] = 0.f;

    const float* nb = nodes + (size_t)b * NNODE * FEATN;
    const float* ab = agg1 + (size_t)b * 256 * FEATN;
    int Tb = T[b];

    for (int kc = 0; kc < 16; ++kc) {
        int kbase = kc * 32;
        __syncthreads();
        // stage XS: 64 rows x 8 float4 (=32 k) ; slot -> (r = slot>>3, k4 = slot&7)
#pragma unroll
        for (int s = 0; s < 2; ++s) {
            int slot = tid + s * 256;
            int k4 = slot & 7;
            int r = slot >> 3;
            int R = tile * 64 + r;
            int k = kbase + k4 * 4;
            float4 v = make_float4(0.f, 0.f, 0.f, 0.f);
            if (R < 272) {
                if (k < 256) {
                    int nrow = (R < 256) ? R : (Tb + R - 256);
                    v = *(const float4*)(nb + (size_t)nrow * FEATN + k);
                } else {
                    int arow;
                    if (R < 256) arow = R;
                    else { int d = Tb + R - 256; arow = (d < 256) ? d : -1; }
                    if (arow >= 0) v = *(const float4*)(ab + (size_t)arow * FEATN + (k - 256));
                }
            }
            *(float4*)(&XS[r][k4 * 4]) = v;
        }
        __syncthreads();
        const float* W = (kbase < 256) ? (Ws + (size_t)kbase * FEATN)
                                       : (Wm + (size_t)(kbase - 256) * FEATN);
#pragma unroll
        for (int k4 = 0; k4 < 8; ++k4) {
            float wv[4][4];
#pragma unroll
            for (int kk = 0; kk < 4; ++kk)
#pragma unroll
                for (int m = 0; m < 4; ++m)
                    wv[kk][m] = W[(size_t)(k4 * 4 + kk) * FEATN + c + m * 64];
#pragma unroll
            for (int r = 0; r < 16; ++r) {
                float4 xv = *(const float4*)(&XS[rg * 16 + r][k4 * 4]);
                float xa0 = xv.x, xa1 = xv.y, xa2 = xv.z, xa3 = xv.w;
#pragma unroll
                for (int m = 0; m < 4; ++m) {
                    acc[r][m] = fmaf(xa0, wv[0][m], acc[r][m]);
                    acc[r][m] = fmaf(xa1, wv[1][m], acc[r][m]);
                    acc[r][m] = fmaf(xa2, wv[2][m], acc[r][m]);
                    acc[r][m] = fmaf(xa3, wv[3][m], acc[r][m]);
                }
            }
        }
    }
#pragma unroll
    for (int r = 0; r < 16; ++r) {
        int R = tile * 64 + rg * 16 + r;
        if (R < 272) {
            float* outp = h1 + ((size_t)b * 272 + R) * FEATN;
#pragma unroll
            for (int m = 0; m < 4; ++m)
                outp[c + m * 64] = tanhf(acc[r][m]);
        }
    }
}

// ---------------- agg2: wave per (b, i window row) ----------------

__global__ void k_agg2(const float* __restrict__ h1, const int2* __restrict__ sw,
                       const int* __restrict__ bstart, const int* __restrict__ T,
                       float* __restrict__ agg2) {
    int gid = blockIdx.x * 4 + (threadIdx.x >> 6);  // 0..2047
    int lane = threadIdx.x & 63;
    int b = gid >> 4, i = gid & 15;
    int d = T[b] + i;
    float4 acc = make_float4(0.f, 0.f, 0.f, 0.f);
    if (d < 256) {
        int e0 = bstart[b * 264 + d];
        int e1 = bstart[b * 264 + d + 1];
        const float4* hb = (const float4*)(h1 + (size_t)b * 272 * FEATN);
        const int2* swb = sw + (size_t)b * NEDGE;
        for (int e = e0; e < e1; ++e) {
            int2 p = swb[e];
            float wt = __int_as_float(p.y);
            float4 vv = hb[p.x * 64 + lane];
            acc.x = fmaf(wt, vv.x, acc.x);
            acc.y = fmaf(wt, vv.y, acc.y);
            acc.z = fmaf(wt, vv.z, acc.z);
            acc.w = fmaf(wt, vv.w, acc.w);
        }
    }
    ((float4*)(agg2 + (size_t)gid * FEATN))[lane] = acc;
}

// ---------------- gemm3: mx = tanh(h1_window @ Ws2 + agg2 @ Wm2) ----------------
// M = 2048 rows (b*16+i), M-tile 16, microtile 4 rows x 4 cols, K=512

__launch_bounds__(256, 2)
__global__ void k_gemm3(const float* __restrict__ h1, const float* __restrict__ agg2,
                        const float* __restrict__ Ws, const float* __restrict__ Wm,
                        float* __restrict__ mx) {
    int tile = blockIdx.x;   // 0..127
    int tid = threadIdx.x;
    int c = tid & 63;
    int rg = tid >> 6;       // rows rg*4..+3 within tile
    __shared__ float XS[16][36];
    float acc[4][4];
#pragma unroll
    for (int r = 0; r < 4; ++r)
#pragma unroll
        for (int m = 0; m < 4; ++m) acc[r][m] = 0.f;

    for (int kc = 0; kc < 16; ++kc) {
        int kbase = kc * 32;
        __syncthreads();
        if (tid < 128) {   // 16 rows x 8 float4
            int k4 = tid & 7;
            int r = tid >> 3;
            int R = tile * 16 + r;
            int b = R >> 4, i = R & 15;
            int k = kbase + k4 * 4;
            float4 v;
            if (k < 256)
                v = *(const float4*)(h1 + ((size_t)b * 272 + 256 + i) * FEATN + k);
            else
                v = *(const float4*)(agg2 + (size_t)R * FEATN + (k - 256));
            *(float4*)(&XS[r][k4 * 4]) = v;
        }
        __syncthreads();
        const float* W = (kbase < 256) ? (Ws + (size_t)kbase * FEATN)
                                       : (Wm + (size_t)(kbase - 256) * FEATN);
#pragma unroll
        for (int k4 = 0; k4 < 8; ++k4) {
            float wv[4][4];
#pragma unroll
            for (int kk = 0; kk < 4; ++kk)
#pragma unroll
                for (int m = 0; m < 4; ++m)
                    wv[kk][m] = W[(size_t)(k4 * 4 + kk) * FEATN + c + m * 64];
#pragma unroll
            for (int r = 0; r < 4; ++r) {
                float4 xv = *(const float4*)(&XS[rg * 4 + r][k4 * 4]);
                float xa0 = xv.x, xa1 = xv.y, xa2 = xv.z, xa3 = xv.w;
#pragma unroll
                for (int m = 0; m < 4; ++m) {
                    acc[r][m] = fmaf(xa0, wv[0][m], acc[r][m]);
                    acc[r][m] = fmaf(xa1, wv[1][m], acc[r][m]);
                    acc[r][m] = fmaf(xa2, wv[2][m], acc[r][m]);
                    acc[r][m] = fmaf(xa3, wv[3][m], acc[r][m]);
                }
            }
        }
    }
#pragma unroll
    for (int r = 0; r < 4; ++r) {
        int R = tile * 16 + rg * 4 + r;
        float* outp = mx + (size_t)R * FEATN;
#pragma unroll
        for (int m = 0; m < 4; ++m)
            outp[c + m * 64] = tanhf(acc[r][m]);
    }
}

// ---------------- launcher ----------------

extern "C" void kernel_launch(void* const* d_in, const int* in_sizes, int n_in,
                              void* d_out, int out_size, void* d_ws, size_t ws_size,
                              hipStream_t stream) {
    const float* x       = (const float*)d_in[0];
    const int*   taus    = (const int*)d_in[1];
    const float* nodes   = (const float*)d_in[2];
    const int*   edges   = (const int*)d_in[3];
    const float* weights = (const float*)d_in[4];
    const int*   T       = (const int*)d_in[5];
    const float* Ws1     = (const float*)d_in[6];
    const float* Wm1     = (const float*)d_in[7];
    const float* Ws2     = (const float*)d_in[8];
    const float* Wm2     = (const float*)d_in[9];
    float* out = (float*)d_out;

    // workspace layout (bytes): needs ~79.9 MB
    char* ws = (char*)d_ws;
    int2*  sw     = (int2*)ws;                           // 8,388,608 B
    int*   bstart = (int*)(ws + 8388608);                // 135,168 B
    float* agg1   = (float*)(ws + 8523776);              // 33,554,432 B
    float* h1     = (float*)(ws + 42078208);             // 35,651,584 B
    float* agg2   = (float*)(ws + 77729792);             // 2,097,152 B

    float* out_nodes = out + OUT_NODES;

    k_copy_nodes<<<4096, 256, 0, stream>>>((const float4*)nodes, (float4*)out_nodes,
                                           BB * NNODE * FEATN / 4);
    k_scatter_x<<<512, 256, 0, stream>>>((const float4*)x, T, (float4*)out_nodes);
    k_misc<<<8192, 256, 0, stream>>>(edges, weights, T, taus, out);
    k_bucket<<<BB, 256, 0, stream>>>(edges, weights, sw, bstart);
    k_agg1<<<BB * 64, 256, 0, stream>>>(out_nodes, sw, bstart, agg1);
    k_gemm1<<<BB * 5, 256, 0, stream>>>(out_nodes, agg1, Ws1, Wm1, T, h1);
    k_agg2<<<512, 256, 0, stream>>>(h1, sw, bstart, T, agg2);
    k_gemm3<<<128, 256, 0, stream>>>(h1, agg2, Ws2, Wm2, out);
}

// Round 2
// 470.017 us; speedup vs baseline: 1.4919x; 1.4919x over previous
//
#include <hip/hip_runtime.h>
#include <math.h>

// Problem constants
#define BB    128
#define TTW   16
#define FEATN 256
#define NNODE 1024
#define NEDGE 8192
#define MROW  272               // 256 referenced rows + 16 window rows per batch
#define M1    (BB*MROW)         // 34816 rows, gemm1 M (272 tiles of 128)
#define M2    (BB*TTW)          // 2048 rows, gemm2 M (16 tiles of 128)

// d_out layout (float elements)
#define OUT_MX    0
#define OUT_NODES (BB*TTW*FEATN)
#define OUT_EDGES (OUT_NODES + BB*NNODE*FEATN)
#define OUT_W     (OUT_EDGES + BB*2*NEDGE)
#define OUT_TT    (OUT_W + BB*NEDGE)

typedef short bf16x8 __attribute__((ext_vector_type(8)));
typedef float f32x4  __attribute__((ext_vector_type(4)));

__device__ inline unsigned short f2bf(float f) {           // RNE fp32->bf16
    unsigned int u = __float_as_uint(f);
    return (unsigned short)((u + 0x7fffu + ((u >> 16) & 1u)) >> 16);
}
__device__ inline float tanh_fast(float x) {               // exact at |x| large
    return 1.f - 2.f / (__expf(2.f * x) + 1.f);
}

// ---------- fused nodes passthrough + x scatter ----------
__global__ void k_pass(const float4* __restrict__ nodes4, const float4* __restrict__ x4,
                       const int* __restrict__ T, float4* __restrict__ out4) {
    int idx = blockIdx.x * 256 + threadIdx.x;      // 8,388,608 float4s
    int b   = idx >> 16;                           // 65536 f4/batch
    int row = (idx >> 6) & 1023;
    int f   = idx & 63;
    int dT  = row - T[b];
    const float4* src = ((unsigned)dT < 16u) ? (x4 + ((size_t)b * 16 + dT) * 64 + f)
                                             : (nodes4 + idx);
    out4[idx] = *src;
}

// ---------- edges/weights/T passthrough (vectorized) ----------
__global__ void k_misc(const int4* __restrict__ e4, const float4* __restrict__ w4,
                       const int* __restrict__ T, const int* __restrict__ taus,
                       float* __restrict__ out) {
    int i = blockIdx.x * 256 + threadIdx.x;
    if (i < 524288) {
        int4 e = e4[i];
        float4 o = make_float4((float)e.x, (float)e.y, (float)e.z, (float)e.w);
        ((float4*)(out + OUT_EDGES))[i] = o;
    } else if (i < 786432) {
        ((float4*)(out + OUT_W))[i - 524288] = w4[i - 524288];
    } else if (i < 786560) {
        int b = i - 786432;
        out[OUT_TT + b] = (float)(T[b] + taus[b]);
    }
}

// ---------- W -> bf16, transposed to [n][k] with k = [Ws rows | Wm rows] ----------
__global__ void k_wconv(const float* __restrict__ Ws1, const float* __restrict__ Wm1,
                        const float* __restrict__ Ws2, const float* __restrict__ Wm2,
                        unsigned short* __restrict__ Wt1, unsigned short* __restrict__ Wt2) {
    int i = blockIdx.x * 256 + threadIdx.x;        // 262144
    int layer = i >> 17;
    int j = i & 131071;
    int k = j >> 8, n = j & 255;                   // coalesced read over n
    const float* Ws = layer ? Ws2 : Ws1;
    const float* Wm = layer ? Wm2 : Wm1;
    float v = (k < 256) ? Ws[(size_t)k * 256 + n] : Wm[(size_t)(k - 256) * 256 + n];
    unsigned short* Wt = layer ? Wt2 : Wt1;
    Wt[(size_t)n * 512 + k] = f2bf(v);
}

// ---------- Xcat1[:, 0:256] = bf16 post-scatter node rows ----------
__global__ void k_prep_x(const float* __restrict__ nodes, const float* __restrict__ x,
                         const int* __restrict__ T, unsigned short* __restrict__ Xc1) {
    int idx = blockIdx.x * 256 + threadIdx.x;      // 34816*32 = 1,114,112 chunks of 8
    int g  = idx >> 5;
    int c8 = idx & 31;
    int b = g / MROW, r = g % MROW;
    int Tb = T[b];
    const float* src;
    if (r >= 256)                       src = x + ((size_t)b * 16 + (r - 256)) * 256;
    else if ((unsigned)(r - Tb) < 16u)  src = x + ((size_t)b * 16 + (r - Tb)) * 256;
    else                                src = nodes + ((size_t)b * 1024 + r) * 256;
    float4 v0 = *(const float4*)(src + c8 * 8);
    float4 v1 = *(const float4*)(src + c8 * 8 + 4);
    uint4 p;
    p.x = f2bf(v0.x) | ((unsigned)f2bf(v0.y) << 16);
    p.y = f2bf(v0.z) | ((unsigned)f2bf(v0.w) << 16);
    p.z = f2bf(v1.x) | ((unsigned)f2bf(v1.y) << 16);
    p.w = f2bf(v1.z) | ((unsigned)f2bf(v1.w) << 16);
    *(uint4*)(Xc1 + (size_t)g * 512 + c8 * 8) = p;
}

// ---------- counting-sort edges by dst (per batch) ----------
__global__ void k_bucket(const int* __restrict__ edges, const float* __restrict__ w,
                         int2* __restrict__ sw, int* __restrict__ bstart) {
    int b = blockIdx.x, tid = threadIdx.x;
    __shared__ int cnt[256];
    __shared__ int pos[256];
    cnt[tid] = 0;
    __syncthreads();
    const int* src = edges + (size_t)b * 2 * NEDGE;
    const int* dst = src + NEDGE;
    for (int e = tid; e < NEDGE; e += 256) atomicAdd(&cnt[dst[e]], 1);
    __syncthreads();
    int my = cnt[tid], v = my;
    for (int off = 1; off < 256; off <<= 1) {
        int u = 0;
        if (tid >= off) u = cnt[tid - off];
        __syncthreads();
        cnt[tid] = v = v + u;
        __syncthreads();
    }
    int start = v - my;
    bstart[b * 264 + tid] = start;
    if (tid == 0) bstart[b * 264 + 256] = NEDGE;
    pos[tid] = start;
    __syncthreads();
    const float* wb = w + (size_t)b * NEDGE;
    for (int e = tid; e < NEDGE; e += 256) {
        int d = dst[e];
        int p = atomicAdd(&pos[d], 1);
        sw[(size_t)b * NEDGE + p] = make_int2(src[e], __float_as_int(wb[e]));
    }
}

// ---------- agg1: wave per Xcat1 row, gather bf16 node rows, write bf16 agg ----------
__global__ void k_agg1(const int2* __restrict__ sw, const int* __restrict__ bstart,
                       const int* __restrict__ T, unsigned short* __restrict__ Xc1) {
    int wid  = blockIdx.x * 4 + (threadIdx.x >> 6);    // 0..34815
    int lane = threadIdx.x & 63;
    int b = wid / MROW, r = wid % MROW;
    int d = (r < 256) ? r : (T[b] + (r - 256));
    float4 acc = make_float4(0.f, 0.f, 0.f, 0.f);
    if (d < 256) {
        int e0 = bstart[b * 264 + d];
        int e1 = bstart[b * 264 + d + 1];
        const int2* swb = sw + (size_t)b * NEDGE;
        const unsigned short* Xb = Xc1 + (size_t)b * MROW * 512;
        for (int e = e0; e < e1; ++e) {
            int2 p = swb[e];
            float wt = __int_as_float(p.y);
            uint2 q = *((const uint2*)(Xb + (size_t)p.x * 512) + lane);   // 4 bf16
            acc.x = fmaf(wt, __uint_as_float(q.x << 16),          acc.x);
            acc.y = fmaf(wt, __uint_as_float(q.x & 0xffff0000u),  acc.y);
            acc.z = fmaf(wt, __uint_as_float(q.y << 16),          acc.z);
            acc.w = fmaf(wt, __uint_as_float(q.y & 0xffff0000u),  acc.w);
        }
    }
    uint2 o;
    o.x = f2bf(acc.x) | ((unsigned)f2bf(acc.y) << 16);
    o.y = f2bf(acc.z) | ((unsigned)f2bf(acc.w) << 16);
    *(uint2*)(Xc1 + (size_t)wid * 512 + 256 + lane * 4) = o;
}

// ---------- MFMA GEMM: out = tanh(Xc[M][512] @ W) ; W given as Wt[n][k] bf16 ----------
// 128x128 tile, 4 waves in 2x2, each wave 4x4 tiles of mfma_f32_16x16x32_bf16
template <int OBF16>
__global__ __launch_bounds__(256, 2) void k_gemm(const unsigned short* __restrict__ Xc,
                                                 const unsigned short* __restrict__ Wt,
                                                 void* __restrict__ outp) {
    int tile_m = blockIdx.x >> 1;
    int tile_n = blockIdx.x & 1;
    int tid  = threadIdx.x;
    int wv   = tid >> 6, lane = tid & 63;
    int wm   = wv >> 1, wn = wv & 1;
    int lm   = lane & 15, lq = lane >> 4;

    __shared__ short As[128 * 32];
    __shared__ short Bs[128 * 32];

    f32x4 acc[4][4];
#pragma unroll
    for (int mi = 0; mi < 4; ++mi)
#pragma unroll
        for (int ni = 0; ni < 4; ++ni) acc[mi][ni] = (f32x4){0.f, 0.f, 0.f, 0.f};

    for (int kc = 0; kc < 16; ++kc) {
        if (kc) __syncthreads();
#pragma unroll
        for (int p = 0; p < 2; ++p) {
            int slot = p * 256 + tid;           // 0..511
            int row = slot >> 2, seg = slot & 3;
            ((uint4*)As)[slot] = *(const uint4*)(Xc + ((size_t)(tile_m * 128 + row)) * 512 + kc * 32 + seg * 8);
            ((uint4*)Bs)[slot] = *(const uint4*)(Wt + ((size_t)(tile_n * 128 + row)) * 512 + kc * 32 + seg * 8);
        }
        __syncthreads();

        bf16x8 af[4], bfr[4];
#pragma unroll
        for (int mi = 0; mi < 4; ++mi)
            af[mi] = ((const bf16x8*)As)[(wm * 64 + mi * 16 + lm) * 4 + lq];
#pragma unroll
        for (int ni = 0; ni < 4; ++ni)
            bfr[ni] = ((const bf16x8*)Bs)[(wn * 64 + ni * 16 + lm) * 4 + lq];
#pragma unroll
        for (int mi = 0; mi < 4; ++mi)
#pragma unroll
            for (int ni = 0; ni < 4; ++ni)
                acc[mi][ni] = __builtin_amdgcn_mfma_f32_16x16x32_bf16(af[mi], bfr[ni], acc[mi][ni], 0, 0, 0);
    }

    // epilogue: D element (m,n): m-row = lq*4 + reg, n-col = lm
#pragma unroll
    for (int mi = 0; mi < 4; ++mi) {
#pragma unroll
        for (int ni = 0; ni < 4; ++ni) {
            int n = tile_n * 128 + wn * 64 + ni * 16 + lm;
#pragma unroll
            for (int r = 0; r < 4; ++r) {
                int m = tile_m * 128 + wm * 64 + mi * 16 + lq * 4 + r;
                float v = tanh_fast(acc[mi][ni][r]);
                if (OBF16) ((unsigned short*)outp)[(size_t)m * 256 + n] = f2bf(v);
                else       ((float*)outp)[(size_t)m * 256 + n] = v;
            }
        }
    }
}

// ---------- agg2 + build Xcat2 (window rows only) ----------
__global__ void k_agg2(const unsigned short* __restrict__ h1, const int2* __restrict__ sw,
                       const int* __restrict__ bstart, const int* __restrict__ T,
                       unsigned short* __restrict__ Xc2) {
    int g2   = blockIdx.x * 4 + (threadIdx.x >> 6);    // 0..2047
    int lane = threadIdx.x & 63;
    int b = g2 >> 4, i = g2 & 15;
    // copy h1 window row -> Xc2[:, 0:256]
    ((uint2*)(Xc2 + (size_t)g2 * 512))[lane] =
        ((const uint2*)(h1 + (size_t)(b * MROW + 256 + i) * 256))[lane];
    int d = T[b] + i;
    float4 acc = make_float4(0.f, 0.f, 0.f, 0.f);
    if (d < 256) {
        int e0 = bstart[b * 264 + d];
        int e1 = bstart[b * 264 + d + 1];
        const int2* swb = sw + (size_t)b * NEDGE;
        const unsigned short* hb = h1 + (size_t)b * MROW * 256;
        for (int e = e0; e < e1; ++e) {
            int2 p = swb[e];
            float wt = __int_as_float(p.y);
            uint2 q = *((const uint2*)(hb + (size_t)p.x * 256) + lane);
            acc.x = fmaf(wt, __uint_as_float(q.x << 16),          acc.x);
            acc.y = fmaf(wt, __uint_as_float(q.x & 0xffff0000u),  acc.y);
            acc.z = fmaf(wt, __uint_as_float(q.y << 16),          acc.z);
            acc.w = fmaf(wt, __uint_as_float(q.y & 0xffff0000u),  acc.w);
        }
    }
    uint2 o;
    o.x = f2bf(acc.x) | ((unsigned)f2bf(acc.y) << 16);
    o.y = f2bf(acc.z) | ((unsigned)f2bf(acc.w) << 16);
    *(uint2*)(Xc2 + (size_t)g2 * 512 + 256 + lane * 4) = o;
}

// ---------- launcher ----------
extern "C" void kernel_launch(void* const* d_in, const int* in_sizes, int n_in,
                              void* d_out, int out_size, void* d_ws, size_t ws_size,
                              hipStream_t stream) {
    const float* x       = (const float*)d_in[0];
    const int*   taus    = (const int*)d_in[1];
    const float* nodes   = (const float*)d_in[2];
    const int*   edges   = (const int*)d_in[3];
    const float* weights = (const float*)d_in[4];
    const int*   T       = (const int*)d_in[5];
    const float* Ws1     = (const float*)d_in[6];
    const float* Wm1     = (const float*)d_in[7];
    const float* Ws2     = (const float*)d_in[8];
    const float* Wm2     = (const float*)d_in[9];
    float* out = (float*)d_out;

    // workspace layout (bytes)
    char* ws = (char*)d_ws;
    int2*           sw     = (int2*)ws;                              //  8,388,608
    int*            bstart = (int*)(ws + 8388608);                   //    135,168
    unsigned short* Xc1    = (unsigned short*)(ws + 8523776);        // 35,651,584  [34816][512]
    unsigned short* h1     = (unsigned short*)(ws + 44175360);       // 17,825,792  [34816][256]
    unsigned short* Xc2    = (unsigned short*)(ws + 62001152);       //  2,097,152  [2048][512]
    unsigned short* Wt1    = (unsigned short*)(ws + 64098304);       //    262,144  [256][512]
    unsigned short* Wt2    = (unsigned short*)(ws + 64360448);       //    262,144

    float* out_nodes = out + OUT_NODES;

    k_pass  <<<32768, 256, 0, stream>>>((const float4*)nodes, (const float4*)x, T, (float4*)out_nodes);
    k_misc  <<<3073, 256, 0, stream>>>((const int4*)edges, (const float4*)weights, T, taus, out);
    k_wconv <<<1024, 256, 0, stream>>>(Ws1, Wm1, Ws2, Wm2, Wt1, Wt2);
    k_prep_x<<<4352, 256, 0, stream>>>(nodes, x, T, Xc1);
    k_bucket<<<BB, 256, 0, stream>>>(edges, weights, sw, bstart);
    k_agg1  <<<8704, 256, 0, stream>>>(sw, bstart, T, Xc1);
    k_gemm<1><<<272 * 2, 256, 0, stream>>>(Xc1, Wt1, h1);
    k_agg2  <<<512, 256, 0, stream>>>(h1, sw, bstart, T, Xc2);
    k_gemm<0><<<16 * 2, 256, 0, stream>>>(Xc2, Wt2, out + OUT_MX);
}

// Round 3
// 463.919 us; speedup vs baseline: 1.5115x; 1.0131x over previous
//
#include <hip/hip_runtime.h>
#include <math.h>

// Problem constants
#define BB    128
#define TTW   16
#define FEATN 256
#define NNODE 1024
#define NEDGE 8192
#define MROW  272               // 256 referenced rows + 16 window rows per batch
#define M1    (BB*MROW)         // 34816 rows

// d_out layout (float elements)
#define OUT_MX    0
#define OUT_NODES (BB*TTW*FEATN)
#define OUT_EDGES (OUT_NODES + BB*NNODE*FEATN)
#define OUT_W     (OUT_EDGES + BB*2*NEDGE)
#define OUT_TT    (OUT_W + BB*NEDGE)

typedef short bf16x8 __attribute__((ext_vector_type(8)));
typedef float f32x4  __attribute__((ext_vector_type(4)));

__device__ inline unsigned short f2bf(float f) {           // RNE fp32->bf16
    unsigned int u = __float_as_uint(f);
    return (unsigned short)((u + 0x7fffu + ((u >> 16) & 1u)) >> 16);
}
__device__ inline float tanh_fast(float x) {
    return 1.f - 2.f / (__expf(2.f * x) + 1.f);
}

// ---------- fused nodes passthrough + x scatter ----------
__global__ void k_pass(const float4* __restrict__ nodes4, const float4* __restrict__ x4,
                       const int* __restrict__ T, float4* __restrict__ out4) {
    int idx = blockIdx.x * 256 + threadIdx.x;      // 8,388,608 float4s
    int b   = idx >> 16;
    int row = (idx >> 6) & 1023;
    int f   = idx & 63;
    int dT  = row - T[b];
    const float4* src = ((unsigned)dT < 16u) ? (x4 + ((size_t)b * 16 + dT) * 64 + f)
                                             : (nodes4 + idx);
    out4[idx] = *src;
}

// ---------- edges/weights/T passthrough ----------
__global__ void k_misc(const int4* __restrict__ e4, const float4* __restrict__ w4,
                       const int* __restrict__ T, const int* __restrict__ taus,
                       float* __restrict__ out) {
    int i = blockIdx.x * 256 + threadIdx.x;
    if (i < 524288) {
        int4 e = e4[i];
        float4 o = make_float4((float)e.x, (float)e.y, (float)e.z, (float)e.w);
        ((float4*)(out + OUT_EDGES))[i] = o;
    } else if (i < 786432) {
        ((float4*)(out + OUT_W))[i - 524288] = w4[i - 524288];
    } else if (i < 786560) {
        int b = i - 786432;
        out[OUT_TT + b] = (float)(T[b] + taus[b]);
    }
}

// ---------- W -> bf16, transposed to [n][k], k = [Ws rows | Wm rows] ----------
__global__ void k_wconv(const float* __restrict__ Ws1, const float* __restrict__ Wm1,
                        const float* __restrict__ Ws2, const float* __restrict__ Wm2,
                        unsigned short* __restrict__ Wt1, unsigned short* __restrict__ Wt2) {
    int i = blockIdx.x * 256 + threadIdx.x;
    int layer = i >> 17;
    int j = i & 131071;
    int k = j >> 8, n = j & 255;
    const float* Ws = layer ? Ws2 : Ws1;
    const float* Wm = layer ? Wm2 : Wm1;
    float v = (k < 256) ? Ws[(size_t)k * 256 + n] : Wm[(size_t)(k - 256) * 256 + n];
    unsigned short* Wt = layer ? Wt2 : Wt1;
    Wt[(size_t)n * 512 + k] = f2bf(v);
}

// ---------- Xcat1[:, 0:256] = bf16 post-scatter node rows ----------
__global__ void k_prep_x(const float* __restrict__ nodes, const float* __restrict__ x,
                         const int* __restrict__ T, unsigned short* __restrict__ Xc1) {
    int idx = blockIdx.x * 256 + threadIdx.x;      // 34816*32
    int g  = idx >> 5;
    int c8 = idx & 31;
    int b = g / MROW, r = g % MROW;
    int Tb = T[b];
    const float* src;
    if (r >= 256)                       src = x + ((size_t)b * 16 + (r - 256)) * 256;
    else if ((unsigned)(r - Tb) < 16u)  src = x + ((size_t)b * 16 + (r - Tb)) * 256;
    else                                src = nodes + ((size_t)b * 1024 + r) * 256;
    float4 v0 = *(const float4*)(src + c8 * 8);
    float4 v1 = *(const float4*)(src + c8 * 8 + 4);
    uint4 p;
    p.x = f2bf(v0.x) | ((unsigned)f2bf(v0.y) << 16);
    p.y = f2bf(v0.z) | ((unsigned)f2bf(v0.w) << 16);
    p.z = f2bf(v1.x) | ((unsigned)f2bf(v1.y) << 16);
    p.w = f2bf(v1.z) | ((unsigned)f2bf(v1.w) << 16);
    *(uint4*)(Xc1 + (size_t)g * 512 + c8 * 8) = p;
}

// ---------- transpose X (rows 0..255 per batch) -> Xt[b][f][s] ----------
__global__ void k_xt(const unsigned short* __restrict__ Xc1, unsigned short* __restrict__ Xt) {
    int b  = blockIdx.x >> 4;
    int tr = (blockIdx.x >> 2) & 3;    // s tile
    int tc = blockIdx.x & 3;           // f tile
    __shared__ unsigned short S[64][72];
#pragma unroll
    for (int p = 0; p < 2; ++p) {
        int slot = p * 256 + threadIdx.x;
        int r = slot >> 3, c8 = slot & 7;
        uint4 v = *(const uint4*)(Xc1 + ((size_t)(b * MROW + tr * 64 + r)) * 512 + tc * 64 + c8 * 8);
        *(uint4*)&S[r][c8 * 8] = v;
    }
    __syncthreads();
#pragma unroll
    for (int p = 0; p < 2; ++p) {
        int slot = p * 256 + threadIdx.x;
        int r2 = slot >> 3, c8 = slot & 7;
        unsigned short tmp[8];
#pragma unroll
        for (int j = 0; j < 8; ++j) tmp[j] = S[c8 * 8 + j][r2];
        *(uint4*)(Xt + ((size_t)b << 16) + (size_t)(tc * 64 + r2) * 256 + tr * 64 + c8 * 8) = *(uint4*)tmp;
    }
}

// ---------- zero W_adj ----------
__global__ void k_zero(float4* __restrict__ p) {
    int i = blockIdx.x * 256 + threadIdx.x;        // 2,097,152
    p[i] = make_float4(0.f, 0.f, 0.f, 0.f);
}

// ---------- scatter-add edge weights into dense per-batch adjacency ----------
__global__ void k_adj(const int* __restrict__ edges, const float* __restrict__ w,
                      float* __restrict__ W_adj) {
    int i = blockIdx.x * 256 + threadIdx.x;        // 1,048,576
    int b = i >> 13, e = i & 8191;
    const int* eb = edges + (size_t)b * 2 * NEDGE;
    int s = eb[e], d = eb[NEDGE + e];
    atomicAdd(&W_adj[((size_t)b << 16) + (d << 8) + s], w[(size_t)b * NEDGE + e]);
}

// ---------- counting-sort edges by dst (per batch) -- for layer-2 gather ----------
__global__ void k_bucket(const int* __restrict__ edges, const float* __restrict__ w,
                         int2* __restrict__ sw, int* __restrict__ bstart) {
    int b = blockIdx.x, tid = threadIdx.x;
    __shared__ int cnt[256];
    __shared__ int pos[256];
    cnt[tid] = 0;
    __syncthreads();
    const int* src = edges + (size_t)b * 2 * NEDGE;
    const int* dst = src + NEDGE;
    for (int e = tid; e < NEDGE; e += 256) atomicAdd(&cnt[dst[e]], 1);
    __syncthreads();
    int my = cnt[tid], v = my;
    for (int off = 1; off < 256; off <<= 1) {
        int u = 0;
        if (tid >= off) u = cnt[tid - off];
        __syncthreads();
        cnt[tid] = v = v + u;
        __syncthreads();
    }
    int start = v - my;
    bstart[b * 264 + tid] = start;
    if (tid == 0) bstart[b * 264 + 256] = NEDGE;
    pos[tid] = start;
    __syncthreads();
    const float* wb = w + (size_t)b * NEDGE;
    for (int e = tid; e < NEDGE; e += 256) {
        int d = dst[e];
        int p = atomicAdd(&pos[d], 1);
        sw[(size_t)b * NEDGE + p] = make_int2(src[e], __float_as_int(wb[e]));
    }
}

// ---------- batched MFMA GEMM: Agg[b] = W_adj[b] @ X[b] -> Xc1[:,256:512] ----------
__global__ __launch_bounds__(256, 2) void k_aggemm(const float* __restrict__ W_adj,
                                                   const unsigned short* __restrict__ Xt,
                                                   unsigned short* __restrict__ Xc1) {
    int b = blockIdx.x >> 2;
    int tile_m = (blockIdx.x >> 1) & 1, tile_n = blockIdx.x & 1;
    int tid = threadIdx.x;
    int wv = tid >> 6, lane = tid & 63;
    int wm = wv >> 1, wn = wv & 1;
    int lm = lane & 15, lq = lane >> 4;

    __shared__ short As[128 * 32];
    __shared__ short Bs[128 * 32];

    f32x4 acc[4][4];
#pragma unroll
    for (int mi = 0; mi < 4; ++mi)
#pragma unroll
        for (int ni = 0; ni < 4; ++ni) acc[mi][ni] = (f32x4){0.f, 0.f, 0.f, 0.f};

    const float* Ab = W_adj + ((size_t)b << 16) + (size_t)tile_m * 128 * 256;
    const unsigned short* Bb = Xt + ((size_t)b << 16) + (size_t)tile_n * 128 * 256;

    for (int kc = 0; kc < 8; ++kc) {
        if (kc) __syncthreads();
        // A: 128 rows x 32 f32, converted to bf16 on the fly
#pragma unroll
        for (int p = 0; p < 4; ++p) {
            int slot = p * 256 + tid;          // 0..1023
            int row = slot >> 3, seg = slot & 7;
            float4 v = *(const float4*)(Ab + (size_t)row * 256 + kc * 32 + seg * 4);
            uint2 pk;
            pk.x = f2bf(v.x) | ((unsigned)f2bf(v.y) << 16);
            pk.y = f2bf(v.z) | ((unsigned)f2bf(v.w) << 16);
            *(uint2*)(As + row * 32 + seg * 4) = pk;
        }
        // B: 128 rows x 32 bf16
#pragma unroll
        for (int p = 0; p < 2; ++p) {
            int slot = p * 256 + tid;          // 0..511
            int row = slot >> 2, seg = slot & 3;
            ((uint4*)Bs)[slot] = *(const uint4*)(Bb + (size_t)row * 256 + kc * 32 + seg * 8);
        }
        __syncthreads();

        bf16x8 af[4], bfr[4];
#pragma unroll
        for (int mi = 0; mi < 4; ++mi)
            af[mi] = ((const bf16x8*)As)[(wm * 64 + mi * 16 + lm) * 4 + lq];
#pragma unroll
        for (int ni = 0; ni < 4; ++ni)
            bfr[ni] = ((const bf16x8*)Bs)[(wn * 64 + ni * 16 + lm) * 4 + lq];
#pragma unroll
        for (int mi = 0; mi < 4; ++mi)
#pragma unroll
            for (int ni = 0; ni < 4; ++ni)
                acc[mi][ni] = __builtin_amdgcn_mfma_f32_16x16x32_bf16(af[mi], bfr[ni], acc[mi][ni], 0, 0, 0);
    }

#pragma unroll
    for (int mi = 0; mi < 4; ++mi) {
#pragma unroll
        for (int ni = 0; ni < 4; ++ni) {
            int n = tile_n * 128 + wn * 64 + ni * 16 + lm;
#pragma unroll
            for (int r = 0; r < 4; ++r) {
                int m = tile_m * 128 + wm * 64 + mi * 16 + lq * 4 + r;
                Xc1[((size_t)(b * MROW + m)) * 512 + 256 + n] = f2bf(acc[mi][ni][r]);
            }
        }
    }
}

// ---------- window-row agg fixup: Xc1 row 256+i agg = (T+i<256) ? Agg[T+i] : 0 ----------
__global__ void k_fixwin(const int* __restrict__ T, unsigned short* __restrict__ Xc1) {
    int b = blockIdx.x;
    int Tb = T[b];
#pragma unroll
    for (int p = 0; p < 2; ++p) {
        int slot = p * 256 + threadIdx.x;       // 512 slots: 16 rows x 32 chunks
        int i = slot >> 5, c = slot & 31;
        int d = Tb + i;
        uint4 v = make_uint4(0u, 0u, 0u, 0u);
        if (d < 256) v = *(const uint4*)(Xc1 + ((size_t)(b * MROW + d)) * 512 + 256 + c * 8);
        *(uint4*)(Xc1 + ((size_t)(b * MROW + 256 + i)) * 512 + 256 + c * 8) = v;
    }
}

// ---------- MFMA GEMM: out = tanh(Xc[M][512] @ Wt^T) ----------
template <int OBF16>
__global__ __launch_bounds__(256, 2) void k_gemm(const unsigned short* __restrict__ Xc,
                                                 const unsigned short* __restrict__ Wt,
                                                 void* __restrict__ outp) {
    int tile_m = blockIdx.x >> 1;
    int tile_n = blockIdx.x & 1;
    int tid  = threadIdx.x;
    int wv   = tid >> 6, lane = tid & 63;
    int wm   = wv >> 1, wn = wv & 1;
    int lm   = lane & 15, lq = lane >> 4;

    __shared__ short As[128 * 32];
    __shared__ short Bs[128 * 32];

    f32x4 acc[4][4];
#pragma unroll
    for (int mi = 0; mi < 4; ++mi)
#pragma unroll
        for (int ni = 0; ni < 4; ++ni) acc[mi][ni] = (f32x4){0.f, 0.f, 0.f, 0.f};

    for (int kc = 0; kc < 16; ++kc) {
        if (kc) __syncthreads();
#pragma unroll
        for (int p = 0; p < 2; ++p) {
            int slot = p * 256 + tid;
            int row = slot >> 2, seg = slot & 3;
            ((uint4*)As)[slot] = *(const uint4*)(Xc + ((size_t)(tile_m * 128 + row)) * 512 + kc * 32 + seg * 8);
            ((uint4*)Bs)[slot] = *(const uint4*)(Wt + ((size_t)(tile_n * 128 + row)) * 512 + kc * 32 + seg * 8);
        }
        __syncthreads();

        bf16x8 af[4], bfr[4];
#pragma unroll
        for (int mi = 0; mi < 4; ++mi)
            af[mi] = ((const bf16x8*)As)[(wm * 64 + mi * 16 + lm) * 4 + lq];
#pragma unroll
        for (int ni = 0; ni < 4; ++ni)
            bfr[ni] = ((const bf16x8*)Bs)[(wn * 64 + ni * 16 + lm) * 4 + lq];
#pragma unroll
        for (int mi = 0; mi < 4; ++mi)
#pragma unroll
            for (int ni = 0; ni < 4; ++ni)
                acc[mi][ni] = __builtin_amdgcn_mfma_f32_16x16x32_bf16(af[mi], bfr[ni], acc[mi][ni], 0, 0, 0);
    }

#pragma unroll
    for (int mi = 0; mi < 4; ++mi) {
#pragma unroll
        for (int ni = 0; ni < 4; ++ni) {
            int n = tile_n * 128 + wn * 64 + ni * 16 + lm;
#pragma unroll
            for (int r = 0; r < 4; ++r) {
                int m = tile_m * 128 + wm * 64 + mi * 16 + lq * 4 + r;
                float v = tanh_fast(acc[mi][ni][r]);
                if (OBF16) ((unsigned short*)outp)[(size_t)m * 256 + n] = f2bf(v);
                else       ((float*)outp)[(size_t)m * 256 + n] = v;
            }
        }
    }
}

// ---------- agg2 + build Xcat2 (window rows only) ----------
__global__ void k_agg2(const unsigned short* __restrict__ h1, const int2* __restrict__ sw,
                       const int* __restrict__ bstart, const int* __restrict__ T,
                       unsigned short* __restrict__ Xc2) {
    int g2   = blockIdx.x * 4 + (threadIdx.x >> 6);
    int lane = threadIdx.x & 63;
    int b = g2 >> 4, i = g2 & 15;
    ((uint2*)(Xc2 + (size_t)g2 * 512))[lane] =
        ((const uint2*)(h1 + (size_t)(b * MROW + 256 + i) * 256))[lane];
    int d = T[b] + i;
    float4 acc = make_float4(0.f, 0.f, 0.f, 0.f);
    if (d < 256) {
        int e0 = bstart[b * 264 + d];
        int e1 = bstart[b * 264 + d + 1];
        const int2* swb = sw + (size_t)b * NEDGE;
        const unsigned short* hb = h1 + (size_t)b * MROW * 256;
        for (int e = e0; e < e1; ++e) {
            int2 p = swb[e];
            float wt = __int_as_float(p.y);
            uint2 q = *((const uint2*)(hb + (size_t)p.x * 256) + lane);
            acc.x = fmaf(wt, __uint_as_float(q.x << 16),          acc.x);
            acc.y = fmaf(wt, __uint_as_float(q.x & 0xffff0000u),  acc.y);
            acc.z = fmaf(wt, __uint_as_float(q.y << 16),          acc.z);
            acc.w = fmaf(wt, __uint_as_float(q.y & 0xffff0000u),  acc.w);
        }
    }
    uint2 o;
    o.x = f2bf(acc.x) | ((unsigned)f2bf(acc.y) << 16);
    o.y = f2bf(acc.z) | ((unsigned)f2bf(acc.w) << 16);
    *(uint2*)(Xc2 + (size_t)g2 * 512 + 256 + lane * 4) = o;
}

// ---------- launcher ----------
extern "C" void kernel_launch(void* const* d_in, const int* in_sizes, int n_in,
                              void* d_out, int out_size, void* d_ws, size_t ws_size,
                              hipStream_t stream) {
    const float* x       = (const float*)d_in[0];
    const int*   taus    = (const int*)d_in[1];
    const float* nodes   = (const float*)d_in[2];
    const int*   edges   = (const int*)d_in[3];
    const float* weights = (const float*)d_in[4];
    const int*   T       = (const int*)d_in[5];
    const float* Ws1     = (const float*)d_in[6];
    const float* Wm1     = (const float*)d_in[7];
    const float* Ws2     = (const float*)d_in[8];
    const float* Wm2     = (const float*)d_in[9];
    float* out = (float*)d_out;

    // workspace layout (bytes) -- Xt overlaps h1's slot (Xt dead before h1 written)
    char* ws = (char*)d_ws;
    int2*           sw     = (int2*)ws;                              //  8,388,608
    int*            bstart = (int*)(ws + 8388608);                   //    135,168
    unsigned short* Xc1    = (unsigned short*)(ws + 8523776);        // 35,651,584  [34816][512]
    unsigned short* h1     = (unsigned short*)(ws + 44175360);       // 17,825,792  [34816][256]
    unsigned short* Xt     = (unsigned short*)(ws + 44175360);       // 16,777,216  (aliases h1)
    unsigned short* Xc2    = (unsigned short*)(ws + 62001152);       //  2,097,152  [2048][512]
    unsigned short* Wt1    = (unsigned short*)(ws + 64098304);       //    262,144
    unsigned short* Wt2    = (unsigned short*)(ws + 64360448);       //    262,144
    float*          W_adj  = (float*)(ws + 64622592);                // 33,554,432  [128][256][256]

    float* out_nodes = out + OUT_NODES;

    k_pass   <<<32768, 256, 0, stream>>>((const float4*)nodes, (const float4*)x, T, (float4*)out_nodes);
    k_misc   <<<3073, 256, 0, stream>>>((const int4*)edges, (const float4*)weights, T, taus, out);
    k_wconv  <<<1024, 256, 0, stream>>>(Ws1, Wm1, Ws2, Wm2, Wt1, Wt2);
    k_prep_x <<<4352, 256, 0, stream>>>(nodes, x, T, Xc1);
    k_xt     <<<2048, 256, 0, stream>>>(Xc1, Xt);
    k_zero   <<<8192, 256, 0, stream>>>((float4*)W_adj);
    k_adj    <<<4096, 256, 0, stream>>>(edges, weights, W_adj);
    k_bucket <<<BB, 256, 0, stream>>>(edges, weights, sw, bstart);
    k_aggemm <<<512, 256, 0, stream>>>(W_adj, Xt, Xc1);
    k_fixwin <<<BB, 256, 0, stream>>>(T, Xc1);
    k_gemm<1><<<272 * 2, 256, 0, stream>>>(Xc1, Wt1, h1);
    k_agg2   <<<512, 256, 0, stream>>>(h1, sw, bstart, T, Xc2);
    k_gemm<0><<<16 * 2, 256, 0, stream>>>(Xc2, Wt2, out + OUT_MX);
}